// Round 1
// baseline (1447.041 us; speedup 1.0000x reference)
//
#include <hip/hip_runtime.h>

// Problem constants (validated against in_sizes at launch)
#define F_IN 144

// ---------------- utility kernels ----------------
__global__ void zero_i32(int* __restrict__ p, int n) {
    int i = blockIdx.x * blockDim.x + threadIdx.x;
    if (i < n) p[i] = 0;
}
__global__ void zero_f32(float* __restrict__ p, int n) {
    int i = blockIdx.x * blockDim.x + threadIdx.x;
    if (i < n) p[i] = 0.f;
}
__global__ void copy_i32(const int* __restrict__ a, int* __restrict__ b, int n) {
    int i = blockIdx.x * blockDim.x + threadIdx.x;
    if (i < n) b[i] = a[i];
}

// ---------------- CSR build ----------------
__global__ void count_edges(const int* __restrict__ dst, int* __restrict__ counts, int E) {
    int e = blockIdx.x * blockDim.x + threadIdx.x;
    if (e < E) atomicAdd(&counts[dst[e]], 1);
}

__global__ __launch_bounds__(1024) void scan_counts(const int* __restrict__ counts,
                                                    int* __restrict__ rowptr, int N) {
    __shared__ int part[1024];
    int t = threadIdx.x;
    int chunk = (N + 1023) >> 10;
    int beg = t * chunk;
    int end = min(beg + chunk, N);
    int s = 0;
    for (int i = beg; i < end; ++i) s += counts[i];
    part[t] = s;
    __syncthreads();
    for (int off = 1; off < 1024; off <<= 1) {
        int v = (t >= off) ? part[t - off] : 0;
        __syncthreads();
        part[t] += v;
        __syncthreads();
    }
    int run = (t == 0) ? 0 : part[t - 1];
    for (int i = beg; i < end; ++i) { rowptr[i] = run; run += counts[i]; }
    if (end == N) rowptr[N] = run;  // multiple writers write the same value (=E)
}

__global__ void fill_edges(const int* __restrict__ src, const int* __restrict__ dst,
                           const float* __restrict__ ea, int* __restrict__ fillhead,
                           int* __restrict__ col, float* __restrict__ wv, int E) {
    int e = blockIdx.x * blockDim.x + threadIdx.x;
    if (e < E) {
        int d = dst[e];
        int pos = atomicAdd(&fillhead[d], 1);
        col[pos] = src[e];
        wv[pos]  = ea[e];
    }
}

// ---------------- aggregation: one wave per node, gather over CSR ----------------
__global__ __launch_bounds__(256) void aggregate_k(
    const float4* __restrict__ h, const int* __restrict__ rowptr,
    const int* __restrict__ col, const float* __restrict__ wv,
    float4* __restrict__ out, int N, int F4) {
    int wid  = (int)((blockIdx.x * 256 + threadIdx.x) >> 6);
    int lane = threadIdx.x & 63;
    if (wid >= N) return;
    int beg = rowptr[wid], end = rowptr[wid + 1];
    for (int f = lane; f < F4; f += 64) {
        float4 acc = make_float4(0.f, 0.f, 0.f, 0.f);
        for (int e = beg; e < end; ++e) {
            float  w = wv[e];
            float4 v = h[(size_t)col[e] * F4 + f];
            acc.x = fmaf(w, v.x, acc.x);
            acc.y = fmaf(w, v.y, acc.y);
            acc.z = fmaf(w, v.z, acc.z);
            acc.w = fmaf(w, v.w, acc.w);
        }
        out[(size_t)wid * F4 + f] = acc;
    }
}

// ---------------- dual-source f32 GEMM ----------------
// C[i][j] = sum_k Aagg[i][k]*Wrel[j][k] + sum_k Ax[i][k]*Wroot[j][k] + bias[j]
// 64x64 tile, BK=16, 256 threads, 4x4 microtile. K must be a multiple of 16.
__global__ __launch_bounds__(256) void gemm_dual(
    const float* __restrict__ Aagg, const float* __restrict__ Ax,
    const float* __restrict__ Wrel, const float* __restrict__ Wroot,
    const float* __restrict__ bias, float* __restrict__ C,
    int M, int K, int Nout, int doRelu) {
    __shared__ float As[16][68];
    __shared__ float Bs[16][68];
    const int tid  = threadIdx.x;
    const int row0 = blockIdx.x * 64;
    const int col0 = blockIdx.y * 64;
    const int lr = tid & 15;        // microtile row group
    const int lc = tid >> 4;        // microtile col group
    const int ldRow = tid >> 2;     // 0..63 (loader row)
    const int ldK   = (tid & 3) << 2;  // 0,4,8,12
    float acc[4][4] = {};
    const int KK = K * 2;
    for (int kk0 = 0; kk0 < KK; kk0 += 16) {
        const float* Asrc; const float* Bsrc; int kof;
        if (kk0 < K) { Asrc = Aagg; Bsrc = Wrel;  kof = kk0; }
        else         { Asrc = Ax;   Bsrc = Wroot; kof = kk0 - K; }
        int ar = row0 + ldRow;
        float4 av = make_float4(0.f, 0.f, 0.f, 0.f);
        if (ar < M) av = *(const float4*)(Asrc + (size_t)ar * K + kof + ldK);
        float4 bv = *(const float4*)(Bsrc + (size_t)(col0 + ldRow) * K + kof + ldK);
        __syncthreads();
        As[ldK + 0][ldRow] = av.x; As[ldK + 1][ldRow] = av.y;
        As[ldK + 2][ldRow] = av.z; As[ldK + 3][ldRow] = av.w;
        Bs[ldK + 0][ldRow] = bv.x; Bs[ldK + 1][ldRow] = bv.y;
        Bs[ldK + 2][ldRow] = bv.z; Bs[ldK + 3][ldRow] = bv.w;
        __syncthreads();
#pragma unroll
        for (int k = 0; k < 16; ++k) {
            float4 a = *(const float4*)&As[k][lr << 2];
            float4 b = *(const float4*)&Bs[k][lc << 2];
            float a4[4] = {a.x, a.y, a.z, a.w};
            float b4[4] = {b.x, b.y, b.z, b.w};
#pragma unroll
            for (int i = 0; i < 4; ++i)
#pragma unroll
                for (int j = 0; j < 4; ++j)
                    acc[i][j] = fmaf(a4[i], b4[j], acc[i][j]);
        }
    }
    float4 bsv = *(const float4*)&bias[col0 + (lc << 2)];
    float bb[4] = {bsv.x, bsv.y, bsv.z, bsv.w};
#pragma unroll
    for (int i = 0; i < 4; ++i) {
        int r = row0 + (lr << 2) + i;
        if (r < M) {
            float4 o;
            o.x = acc[i][0] + bb[0];
            o.y = acc[i][1] + bb[1];
            o.z = acc[i][2] + bb[2];
            o.w = acc[i][3] + bb[3];
            if (doRelu) {
                o.x = fmaxf(o.x, 0.f); o.y = fmaxf(o.y, 0.f);
                o.z = fmaxf(o.z, 0.f); o.w = fmaxf(o.w, 0.f);
            }
            *(float4*)&C[(size_t)r * Nout + col0 + (lc << 2)] = o;
        }
    }
}

// ---------------- GraphNorm (F = 256 fixed) ----------------
__global__ __launch_bounds__(256) void colstats(const float* __restrict__ h,
                                                float* __restrict__ sums,
                                                float* __restrict__ sqs, int N) {
    int f = threadIdx.x;
    float s = 0.f, q = 0.f;
    for (int i = blockIdx.x; i < N; i += gridDim.x) {
        float v = h[(size_t)i * 256 + f];
        s += v;
        q = fmaf(v, v, q);
    }
    atomicAdd(&sums[f], s);
    atomicAdd(&sqs[f], q);
}

__global__ void norm_prep(const float* __restrict__ sums, const float* __restrict__ sqs,
                          const float* __restrict__ gw, const float* __restrict__ gb,
                          const float* __restrict__ gms, float* __restrict__ scaleF,
                          float* __restrict__ shiftF, float invN) {
    int f = threadIdx.x;  // 256 threads
    float mu  = sums[f] * invN;
    float ex2 = sqs[f] * invN;
    float a   = gms[f] * mu;
    float var = ex2 - 2.f * a * mu + a * a;   // E[(x - ms*mu)^2]
    float inv = rsqrtf(var + 1e-5f);
    float sc  = gw[f] * inv;
    scaleF[f] = sc;
    shiftF[f] = gb[f] - a * sc;
}

__global__ __launch_bounds__(256) void norm_apply(float4* __restrict__ h,
                                                  const float4* __restrict__ scaleF,
                                                  const float4* __restrict__ shiftF, int n4) {
    int i = blockIdx.x * 256 + threadIdx.x;
    if (i >= n4) return;
    int f4 = i & 63;  // 256 feats = 64 float4 per row
    float4 v = h[i], sc = scaleF[f4], sh = shiftF[f4];
    v.x = fmaxf(fmaf(v.x, sc.x, sh.x), 0.f);
    v.y = fmaxf(fmaf(v.y, sc.y, sh.y), 0.f);
    v.z = fmaxf(fmaf(v.z, sc.z, sh.z), 0.f);
    v.w = fmaxf(fmaf(v.w, sc.w, sh.w), 0.f);
    h[i] = v;
}

// ---------------- launch ----------------
extern "C" void kernel_launch(void* const* d_in, const int* in_sizes, int n_in,
                              void* d_out, int out_size, void* d_ws, size_t ws_size,
                              hipStream_t stream) {
    const float* x   = (const float*)d_in[0];
    const int*   ei  = (const int*)d_in[1];
    const float* ea  = (const float*)d_in[2];
    const float* Wr1 = (const float*)d_in[3];
    const float* b1  = (const float*)d_in[4];
    const float* Wo1 = (const float*)d_in[5];
    const float* Wr2 = (const float*)d_in[6];
    const float* b2  = (const float*)d_in[7];
    const float* Wo2 = (const float*)d_in[8];
    const float* Wr3 = (const float*)d_in[9];
    const float* b3  = (const float*)d_in[10];
    const float* Wo3 = (const float*)d_in[11];
    const float* Wr4 = (const float*)d_in[12];
    const float* b4  = (const float*)d_in[13];
    const float* Wo4 = (const float*)d_in[14];
    const float* gw  = (const float*)d_in[15];
    const float* gb  = (const float*)d_in[16];
    const float* gms = (const float*)d_in[17];

    const int Nn = in_sizes[0] / F_IN;   // 50000
    const int E  = in_sizes[1] / 2;      // 400000
    const int* src = ei;
    const int* dst = ei + E;

    // workspace carve-out (256B aligned)
    char* w = (char*)d_ws;
    auto alloc = [&](size_t bytes) -> void* {
        void* p = (void*)w;
        w += (bytes + 255) & ~(size_t)255;
        return p;
    };
    int*   counts   = (int*)alloc((size_t)Nn * 4);
    int*   rowptr   = (int*)alloc((size_t)(Nn + 1) * 4);
    int*   fillhead = (int*)alloc((size_t)Nn * 4);
    int*   col      = (int*)alloc((size_t)E * 4);
    float* wv       = (float*)alloc((size_t)E * 4);
    float* stats    = (float*)alloc(1024 * 4);
    float* sums = stats, *sqs = stats + 256, *scaleF = stats + 512, *shiftF = stats + 768;
    float* bufA = (float*)alloc((size_t)Nn * 512 * 4);  // agg buffer (max width 512)
    float* bufB = (float*)alloc((size_t)Nn * 256 * 4);  // h1 / h3 / h4
    float* bufC = (float*)alloc((size_t)Nn * 512 * 4);  // h2

    const int TB = 256;
    // CSR build
    zero_i32<<<(Nn + TB - 1) / TB, TB, 0, stream>>>(counts, Nn);
    count_edges<<<(E + TB - 1) / TB, TB, 0, stream>>>(dst, counts, E);
    scan_counts<<<1, 1024, 0, stream>>>(counts, rowptr, Nn);
    copy_i32<<<(Nn + TB - 1) / TB, TB, 0, stream>>>(rowptr, fillhead, Nn);
    fill_edges<<<(E + TB - 1) / TB, TB, 0, stream>>>(src, dst, ea, fillhead, col, wv, E);

    int aggGrid = (Nn + 3) / 4;  // 4 waves/block, 1 node/wave
    int mBlocks = (Nn + 63) / 64;

    // Layer 1: 144 -> 256, relu
    aggregate_k<<<aggGrid, TB, 0, stream>>>((const float4*)x, rowptr, col, wv,
                                            (float4*)bufA, Nn, 36);
    gemm_dual<<<dim3(mBlocks, 4), TB, 0, stream>>>(bufA, x, Wr1, Wo1, b1, bufB,
                                                   Nn, 144, 256, 1);
    // Layer 2: 256 -> 512, relu
    aggregate_k<<<aggGrid, TB, 0, stream>>>((const float4*)bufB, rowptr, col, wv,
                                            (float4*)bufA, Nn, 64);
    gemm_dual<<<dim3(mBlocks, 8), TB, 0, stream>>>(bufA, bufB, Wr2, Wo2, b2, bufC,
                                                   Nn, 256, 512, 1);
    // Layer 3: 512 -> 256, no relu
    aggregate_k<<<aggGrid, TB, 0, stream>>>((const float4*)bufC, rowptr, col, wv,
                                            (float4*)bufA, Nn, 128);
    gemm_dual<<<dim3(mBlocks, 4), TB, 0, stream>>>(bufA, bufC, Wr3, Wo3, b3, bufB,
                                                   Nn, 512, 256, 0);
    // GraphNorm + relu (in-place on bufB)
    zero_f32<<<2, TB, 0, stream>>>(stats, 512);
    colstats<<<256, TB, 0, stream>>>(bufB, sums, sqs, Nn);
    norm_prep<<<1, 256, 0, stream>>>(sums, sqs, gw, gb, gms, scaleF, shiftF, 1.0f / Nn);
    norm_apply<<<(Nn * 64 + TB - 1) / TB, TB, 0, stream>>>((float4*)bufB,
                                                           (const float4*)scaleF,
                                                           (const float4*)shiftF, Nn * 64);
    // Layer 4: 256 -> 128, no relu
    aggregate_k<<<aggGrid, TB, 0, stream>>>((const float4*)bufB, rowptr, col, wv,
                                            (float4*)bufA, Nn, 64);
    gemm_dual<<<dim3(mBlocks, 2), TB, 0, stream>>>(bufA, bufB, Wr4, Wo4, b4,
                                                   (float*)d_out, Nn, 256, 128, 0);
}

// Round 2
// 1229.644 us; speedup vs baseline: 1.1768x; 1.1768x over previous
//
#include <hip/hip_runtime.h>

#define F_IN 144

typedef __attribute__((ext_vector_type(8))) short short8v;
typedef __attribute__((ext_vector_type(4))) float f32x4;

// ---------------- utility kernels ----------------
__global__ void zero_i32(int* __restrict__ p, int n) {
    int i = blockIdx.x * blockDim.x + threadIdx.x;
    if (i < n) p[i] = 0;
}
__global__ void zero_f32(float* __restrict__ p, int n) {
    int i = blockIdx.x * blockDim.x + threadIdx.x;
    if (i < n) p[i] = 0.f;
}
__global__ void copy_i32(const int* __restrict__ a, int* __restrict__ b, int n) {
    int i = blockIdx.x * blockDim.x + threadIdx.x;
    if (i < n) b[i] = a[i];
}

// ---------------- CSR build ----------------
__global__ void count_edges(const int* __restrict__ dst, int* __restrict__ counts, int E) {
    int e = blockIdx.x * blockDim.x + threadIdx.x;
    if (e < E) atomicAdd(&counts[dst[e]], 1);
}

__global__ __launch_bounds__(1024) void scan_counts(const int* __restrict__ counts,
                                                    int* __restrict__ rowptr, int N) {
    __shared__ int part[1024];
    int t = threadIdx.x;
    int chunk = (N + 1023) >> 10;
    int beg = t * chunk;
    int end = min(beg + chunk, N);
    int s = 0;
    for (int i = beg; i < end; ++i) s += counts[i];
    part[t] = s;
    __syncthreads();
    for (int off = 1; off < 1024; off <<= 1) {
        int v = (t >= off) ? part[t - off] : 0;
        __syncthreads();
        part[t] += v;
        __syncthreads();
    }
    int run = (t == 0) ? 0 : part[t - 1];
    for (int i = beg; i < end; ++i) { rowptr[i] = run; run += counts[i]; }
    if (end == N) rowptr[N] = run;
}

__global__ void fill_edges(const int* __restrict__ src, const int* __restrict__ dst,
                           const float* __restrict__ ea, int* __restrict__ fillhead,
                           int* __restrict__ col, float* __restrict__ wv, int E) {
    int e = blockIdx.x * blockDim.x + threadIdx.x;
    if (e < E) {
        int d = dst[e];
        int pos = atomicAdd(&fillhead[d], 1);
        col[pos] = src[e];
        wv[pos]  = ea[e];
    }
}

// ---------------- aggregation: one wave per node, gather over CSR ----------------
__global__ __launch_bounds__(256) void aggregate_k(
    const float4* __restrict__ h, const int* __restrict__ rowptr,
    const int* __restrict__ col, const float* __restrict__ wv,
    float4* __restrict__ out, int N, int F4) {
    int wid  = (int)((blockIdx.x * 256 + threadIdx.x) >> 6);
    int lane = threadIdx.x & 63;
    if (wid >= N) return;
    int beg = rowptr[wid], end = rowptr[wid + 1];
    for (int f = lane; f < F4; f += 64) {
        float4 acc = make_float4(0.f, 0.f, 0.f, 0.f);
        for (int e = beg; e < end; ++e) {
            float  w = wv[e];
            float4 v = h[(size_t)col[e] * F4 + f];
            acc.x = fmaf(w, v.x, acc.x);
            acc.y = fmaf(w, v.y, acc.y);
            acc.z = fmaf(w, v.z, acc.z);
            acc.w = fmaf(w, v.w, acc.w);
        }
        out[(size_t)wid * F4 + f] = acc;
    }
}

// ---------------- split-bf16 helpers ----------------
__device__ __forceinline__ unsigned short bf16rn(float x) {
    union { float f; unsigned u; } a; a.f = x;
    return (unsigned short)((a.u + 0x7FFFu + ((a.u >> 16) & 1u)) >> 16);
}
__device__ __forceinline__ float bf16tof(unsigned short h) {
    union { float f; unsigned u; } a; a.u = ((unsigned)h) << 16;
    return a.f;
}

// ---------------- dual-source split-bf16 MFMA GEMM ----------------
// C[i][j] = sum_k Aagg[i][k]*Wrel[j][k] + sum_k Ax[i][k]*Wroot[j][k] + bias[j]
// Virtual KK = 2K axis. BM=128, BN=256, BKF=32 f32 per step. 512 thr = 8 waves,
// each wave owns a 64x64 output sub-tile (4x4 frags of 16x16).
// Split bf16: x = hi + lo (both RNE); C ≈ Ah*Bh + Ah*Bl + Al*Bh  (~fp24 accurate).
#define BM 128
#define BN 256
#define BKF 32
#define LSTR 40   // shorts per LDS row (32 + 8 pad -> 80B stride, ~2-way banks)

__global__ __launch_bounds__(512) void gemm_dual_mfma(
    const float* __restrict__ Aagg, const float* __restrict__ Ax,
    const float* __restrict__ Wrel, const float* __restrict__ Wroot,
    const float* __restrict__ bias, float* __restrict__ C,
    int M, int K, int Nout, int doRelu) {
    __shared__ short Ah[BM * LSTR];
    __shared__ short Al[BM * LSTR];
    __shared__ short Bh[BN * LSTR];
    __shared__ short Bl[BN * LSTR];

    const int tid  = threadIdx.x;
    const int lane = tid & 63;
    const int wid  = tid >> 6;      // 0..7
    const int wm   = wid >> 2;      // 0..1  (row half)
    const int wn   = wid & 3;       // 0..3  (col quarter)
    const int lane15 = lane & 15;
    const int slot   = lane >> 4;   // 0..3
    const int row0 = blockIdx.x * BM;
    const int col0 = blockIdx.y * BN;

    f32x4 acc[4][4] = {};
    const int KK = 2 * K;

    for (int kk0 = 0; kk0 < KK; kk0 += BKF) {
        __syncthreads();
        // ---- stage A: 1024 float4, 2 per thread ----
#pragma unroll
        for (int i = 0; i < 2; ++i) {
            int idx = i * 512 + tid;
            int r   = idx >> 3;      // 0..127
            int k4  = idx & 7;
            int kk  = kk0 + k4 * 4;
            int gr  = row0 + r;
            float4 v = make_float4(0.f, 0.f, 0.f, 0.f);
            if (gr < M) {
                const float* s = (kk < K) ? (Aagg + (size_t)gr * K + kk)
                                          : (Ax   + (size_t)gr * K + (kk - K));
                v = *(const float4*)s;
            }
            ushort4 h, l;
            h.x = bf16rn(v.x); l.x = bf16rn(v.x - bf16tof(h.x));
            h.y = bf16rn(v.y); l.y = bf16rn(v.y - bf16tof(h.y));
            h.z = bf16rn(v.z); l.z = bf16rn(v.z - bf16tof(h.z));
            h.w = bf16rn(v.w); l.w = bf16rn(v.w - bf16tof(h.w));
            *(ushort4*)&Ah[r * LSTR + k4 * 4] = h;
            *(ushort4*)&Al[r * LSTR + k4 * 4] = l;
        }
        // ---- stage B: 2048 float4, 4 per thread ----
#pragma unroll
        for (int i = 0; i < 4; ++i) {
            int idx = i * 512 + tid;
            int r   = idx >> 3;      // 0..255
            int k4  = idx & 7;
            int kk  = kk0 + k4 * 4;
            int gc  = col0 + r;
            float4 v = make_float4(0.f, 0.f, 0.f, 0.f);
            if (gc < Nout) {
                const float* s = (kk < K) ? (Wrel  + (size_t)gc * K + kk)
                                          : (Wroot + (size_t)gc * K + (kk - K));
                v = *(const float4*)s;
            }
            ushort4 h, l;
            h.x = bf16rn(v.x); l.x = bf16rn(v.x - bf16tof(h.x));
            h.y = bf16rn(v.y); l.y = bf16rn(v.y - bf16tof(h.y));
            h.z = bf16rn(v.z); l.z = bf16rn(v.z - bf16tof(h.z));
            h.w = bf16rn(v.w); l.w = bf16rn(v.w - bf16tof(h.w));
            *(ushort4*)&Bh[r * LSTR + k4 * 4] = h;
            *(ushort4*)&Bl[r * LSTR + k4 * 4] = l;
        }
        __syncthreads();
        // ---- fragments + MFMA ----
        short8v ah[4], al[4], bh[4], bl[4];
#pragma unroll
        for (int bi = 0; bi < 4; ++bi) {
            int r = wm * 64 + bi * 16 + lane15;
            ah[bi] = *(const short8v*)&Ah[r * LSTR + slot * 8];
            al[bi] = *(const short8v*)&Al[r * LSTR + slot * 8];
        }
#pragma unroll
        for (int bj = 0; bj < 4; ++bj) {
            int c = wn * 64 + bj * 16 + lane15;
            bh[bj] = *(const short8v*)&Bh[c * LSTR + slot * 8];
            bl[bj] = *(const short8v*)&Bl[c * LSTR + slot * 8];
        }
#pragma unroll
        for (int bi = 0; bi < 4; ++bi)
#pragma unroll
            for (int bj = 0; bj < 4; ++bj) {
                acc[bi][bj] = __builtin_amdgcn_mfma_f32_16x16x32_bf16(
                    ah[bi], bh[bj], acc[bi][bj], 0, 0, 0);
                acc[bi][bj] = __builtin_amdgcn_mfma_f32_16x16x32_bf16(
                    ah[bi], bl[bj], acc[bi][bj], 0, 0, 0);
                acc[bi][bj] = __builtin_amdgcn_mfma_f32_16x16x32_bf16(
                    al[bi], bh[bj], acc[bi][bj], 0, 0, 0);
            }
    }
    // ---- epilogue: D row = slot*4+q, col = lane15 ----
#pragma unroll
    for (int bj = 0; bj < 4; ++bj) {
        int cc = col0 + wn * 64 + bj * 16 + lane15;
        float bv = (cc < Nout) ? bias[cc] : 0.f;
#pragma unroll
        for (int bi = 0; bi < 4; ++bi) {
#pragma unroll
            for (int q = 0; q < 4; ++q) {
                int rr = row0 + wm * 64 + bi * 16 + slot * 4 + q;
                if (rr < M && cc < Nout) {
                    float o = acc[bi][bj][q] + bv;
                    if (doRelu) o = fmaxf(o, 0.f);
                    C[(size_t)rr * Nout + cc] = o;
                }
            }
        }
    }
}

// ---------------- GraphNorm (F = 256 fixed) ----------------
__global__ __launch_bounds__(256) void colstats(const float* __restrict__ h,
                                                float* __restrict__ sums,
                                                float* __restrict__ sqs, int N) {
    int f = threadIdx.x;
    float s = 0.f, q = 0.f;
    for (int i = blockIdx.x; i < N; i += gridDim.x) {
        float v = h[(size_t)i * 256 + f];
        s += v;
        q = fmaf(v, v, q);
    }
    atomicAdd(&sums[f], s);
    atomicAdd(&sqs[f], q);
}

__global__ void norm_prep(const float* __restrict__ sums, const float* __restrict__ sqs,
                          const float* __restrict__ gw, const float* __restrict__ gb,
                          const float* __restrict__ gms, float* __restrict__ scaleF,
                          float* __restrict__ shiftF, float invN) {
    int f = threadIdx.x;  // 256 threads
    float mu  = sums[f] * invN;
    float ex2 = sqs[f] * invN;
    float a   = gms[f] * mu;
    float var = ex2 - 2.f * a * mu + a * a;
    float inv = rsqrtf(var + 1e-5f);
    float sc  = gw[f] * inv;
    scaleF[f] = sc;
    shiftF[f] = gb[f] - a * sc;
}

__global__ __launch_bounds__(256) void norm_apply(float4* __restrict__ h,
                                                  const float4* __restrict__ scaleF,
                                                  const float4* __restrict__ shiftF, int n4) {
    int i = blockIdx.x * 256 + threadIdx.x;
    if (i >= n4) return;
    int f4 = i & 63;
    float4 v = h[i], sc = scaleF[f4], sh = shiftF[f4];
    v.x = fmaxf(fmaf(v.x, sc.x, sh.x), 0.f);
    v.y = fmaxf(fmaf(v.y, sc.y, sh.y), 0.f);
    v.z = fmaxf(fmaf(v.z, sc.z, sh.z), 0.f);
    v.w = fmaxf(fmaf(v.w, sc.w, sh.w), 0.f);
    h[i] = v;
}

// ---------------- launch ----------------
extern "C" void kernel_launch(void* const* d_in, const int* in_sizes, int n_in,
                              void* d_out, int out_size, void* d_ws, size_t ws_size,
                              hipStream_t stream) {
    const float* x   = (const float*)d_in[0];
    const int*   ei  = (const int*)d_in[1];
    const float* ea  = (const float*)d_in[2];
    const float* Wr1 = (const float*)d_in[3];
    const float* b1  = (const float*)d_in[4];
    const float* Wo1 = (const float*)d_in[5];
    const float* Wr2 = (const float*)d_in[6];
    const float* b2  = (const float*)d_in[7];
    const float* Wo2 = (const float*)d_in[8];
    const float* Wr3 = (const float*)d_in[9];
    const float* b3  = (const float*)d_in[10];
    const float* Wo3 = (const float*)d_in[11];
    const float* Wr4 = (const float*)d_in[12];
    const float* b4  = (const float*)d_in[13];
    const float* Wo4 = (const float*)d_in[14];
    const float* gw  = (const float*)d_in[15];
    const float* gb  = (const float*)d_in[16];
    const float* gms = (const float*)d_in[17];

    const int Nn = in_sizes[0] / F_IN;   // 50000
    const int E  = in_sizes[1] / 2;      // 400000
    const int* src = ei;
    const int* dst = ei + E;

    char* w = (char*)d_ws;
    auto alloc = [&](size_t bytes) -> void* {
        void* p = (void*)w;
        w += (bytes + 255) & ~(size_t)255;
        return p;
    };
    int*   counts   = (int*)alloc((size_t)Nn * 4);
    int*   rowptr   = (int*)alloc((size_t)(Nn + 1) * 4);
    int*   fillhead = (int*)alloc((size_t)Nn * 4);
    int*   col      = (int*)alloc((size_t)E * 4);
    float* wv       = (float*)alloc((size_t)E * 4);
    float* stats    = (float*)alloc(1024 * 4);
    float* sums = stats, *sqs = stats + 256, *scaleF = stats + 512, *shiftF = stats + 768;
    float* bufA = (float*)alloc((size_t)Nn * 512 * 4);  // agg buffer (max width 512)
    float* bufB = (float*)alloc((size_t)Nn * 256 * 4);  // h1 / h3
    float* bufC = (float*)alloc((size_t)Nn * 512 * 4);  // h2

    const int TB = 256;
    zero_i32<<<(Nn + TB - 1) / TB, TB, 0, stream>>>(counts, Nn);
    count_edges<<<(E + TB - 1) / TB, TB, 0, stream>>>(dst, counts, E);
    scan_counts<<<1, 1024, 0, stream>>>(counts, rowptr, Nn);
    copy_i32<<<(Nn + TB - 1) / TB, TB, 0, stream>>>(rowptr, fillhead, Nn);
    fill_edges<<<(E + TB - 1) / TB, TB, 0, stream>>>(src, dst, ea, fillhead, col, wv, E);

    int aggGrid  = (Nn + 3) / 4;
    int mBlocks  = (Nn + BM - 1) / BM;   // 391

    // Layer 1: 144 -> 256, relu
    aggregate_k<<<aggGrid, TB, 0, stream>>>((const float4*)x, rowptr, col, wv,
                                            (float4*)bufA, Nn, 36);
    gemm_dual_mfma<<<dim3(mBlocks, 1), 512, 0, stream>>>(bufA, x, Wr1, Wo1, b1, bufB,
                                                         Nn, 144, 256, 1);
    // Layer 2: 256 -> 512, relu
    aggregate_k<<<aggGrid, TB, 0, stream>>>((const float4*)bufB, rowptr, col, wv,
                                            (float4*)bufA, Nn, 64);
    gemm_dual_mfma<<<dim3(mBlocks, 2), 512, 0, stream>>>(bufA, bufB, Wr2, Wo2, b2, bufC,
                                                         Nn, 256, 512, 1);
    // Layer 3: 512 -> 256, no relu
    aggregate_k<<<aggGrid, TB, 0, stream>>>((const float4*)bufC, rowptr, col, wv,
                                            (float4*)bufA, Nn, 128);
    gemm_dual_mfma<<<dim3(mBlocks, 1), 512, 0, stream>>>(bufA, bufC, Wr3, Wo3, b3, bufB,
                                                         Nn, 512, 256, 0);
    // GraphNorm + relu (in-place on bufB)
    zero_f32<<<2, TB, 0, stream>>>(stats, 512);
    colstats<<<256, TB, 0, stream>>>(bufB, sums, sqs, Nn);
    norm_prep<<<1, 256, 0, stream>>>(sums, sqs, gw, gb, gms, scaleF, shiftF, 1.0f / Nn);
    norm_apply<<<(Nn * 64 + TB - 1) / TB, TB, 0, stream>>>((float4*)bufB,
                                                           (const float4*)scaleF,
                                                           (const float4*)shiftF, Nn * 64);
    // Layer 4: 256 -> 128, no relu
    aggregate_k<<<aggGrid, TB, 0, stream>>>((const float4*)bufB, rowptr, col, wv,
                                            (float4*)bufA, Nn, 64);
    gemm_dual_mfma<<<dim3(mBlocks, 1), 512, 0, stream>>>(bufA, bufB, Wr4, Wo4, b4,
                                                         (float*)d_out, Nn, 256, 128, 0);
}

// Round 3
// 936.205 us; speedup vs baseline: 1.5456x; 1.3134x over previous
//
#include <hip/hip_runtime.h>

#define F_IN 144
typedef __attribute__((ext_vector_type(8))) short short8v;
typedef __attribute__((ext_vector_type(4))) float f32x4;
typedef unsigned short u16;

// ---------------- bf16 hi/lo helpers ----------------
__device__ __forceinline__ u16 bf16rn(float x) {
    union { float f; unsigned u; } a; a.f = x;
    return (u16)((a.u + 0x7FFFu + ((a.u >> 16) & 1u)) >> 16);
}
__device__ __forceinline__ float bf16tof(u16 h) {
    union { float f; unsigned u; } a; a.u = ((unsigned)h) << 16;
    return a.f;
}
__device__ __forceinline__ void packhl(float v, unsigned short& h, unsigned short& l) {
    h = bf16rn(v);
    l = bf16rn(v - bf16tof(h));
}
__device__ __forceinline__ void gload_lds16(const u16* g, u16* s) {
    __builtin_amdgcn_global_load_lds(
        (const __attribute__((address_space(1))) void*)g,
        (__attribute__((address_space(3))) void*)s, 16, 0, 0);
}

// ---------------- utility ----------------
__global__ void zero_i32(int* __restrict__ p, int n) {
    int i = blockIdx.x * blockDim.x + threadIdx.x;
    if (i < n) p[i] = 0;
}
__global__ void zero_f32(float* __restrict__ p, int n) {
    int i = blockIdx.x * blockDim.x + threadIdx.x;
    if (i < n) p[i] = 0.f;
}
__global__ void copy_i32(const int* __restrict__ a, int* __restrict__ b, int n) {
    int i = blockIdx.x * blockDim.x + threadIdx.x;
    if (i < n) b[i] = a[i];
}
// f32 -> bf16 hi/lo conversion (flat)
__global__ void conv_hl(const float* __restrict__ src, u16* __restrict__ dh,
                        u16* __restrict__ dl, int n) {
    int i = blockIdx.x * 256 + threadIdx.x;
    if (i < n) {
        float v = src[i];
        u16 h = bf16rn(v);
        dh[i] = h;
        dl[i] = bf16rn(v - bf16tof(h));
    }
}

// ---------------- CSR build ----------------
__global__ void count_edges(const int* __restrict__ dst, int* __restrict__ counts, int E) {
    int e = blockIdx.x * blockDim.x + threadIdx.x;
    if (e < E) atomicAdd(&counts[dst[e]], 1);
}

__global__ __launch_bounds__(1024) void scan_counts(const int* __restrict__ counts,
                                                    int* __restrict__ rowptr, int N) {
    __shared__ int part[1024];
    int t = threadIdx.x;
    int chunk = (N + 1023) >> 10;
    int beg = t * chunk;
    int end = min(beg + chunk, N);
    int s = 0;
    for (int i = beg; i < end; ++i) s += counts[i];
    part[t] = s;
    __syncthreads();
    for (int off = 1; off < 1024; off <<= 1) {
        int v = (t >= off) ? part[t - off] : 0;
        __syncthreads();
        part[t] += v;
        __syncthreads();
    }
    int run = (t == 0) ? 0 : part[t - 1];
    for (int i = beg; i < end; ++i) { rowptr[i] = run; run += counts[i]; }
    if (end == N) rowptr[N] = run;
}

__global__ void fill_edges(const int* __restrict__ src, const int* __restrict__ dst,
                           const float* __restrict__ ea, int* __restrict__ fillhead,
                           int* __restrict__ col, float* __restrict__ wv, int E) {
    int e = blockIdx.x * blockDim.x + threadIdx.x;
    if (e < E) {
        int d = dst[e];
        int pos = atomicAdd(&fillhead[d], 1);
        col[pos] = src[e];
        wv[pos]  = ea[e];
    }
}

// ---------------- aggregation over CSR, bf16 hi/lo in & out ----------------
__global__ __launch_bounds__(256) void aggregate_hl(
    const u16* __restrict__ Sh, const u16* __restrict__ Sl,
    const int* __restrict__ rowptr, const int* __restrict__ col,
    const float* __restrict__ wv,
    u16* __restrict__ Dh, u16* __restrict__ Dl, int N, int F4) {
    int wid  = (int)((blockIdx.x * 256 + threadIdx.x) >> 6);
    int lane = threadIdx.x & 63;
    if (wid >= N) return;
    int beg = rowptr[wid], end = rowptr[wid + 1];
    const ushort4* S4h = (const ushort4*)Sh;
    const ushort4* S4l = (const ushort4*)Sl;
    for (int f = lane; f < F4; f += 64) {
        float ax = 0.f, ay = 0.f, az = 0.f, aw = 0.f;
        for (int e = beg; e < end; ++e) {
            float wgt = wv[e];
            size_t b = (size_t)col[e] * F4 + f;
            ushort4 h4 = S4h[b];
            ushort4 l4 = S4l[b];
            ax = fmaf(wgt, bf16tof(h4.x) + bf16tof(l4.x), ax);
            ay = fmaf(wgt, bf16tof(h4.y) + bf16tof(l4.y), ay);
            az = fmaf(wgt, bf16tof(h4.z) + bf16tof(l4.z), az);
            aw = fmaf(wgt, bf16tof(h4.w) + bf16tof(l4.w), aw);
        }
        ushort4 oh, ol;
        packhl(ax, oh.x, ol.x); packhl(ay, oh.y, ol.y);
        packhl(az, oh.z, ol.z); packhl(aw, oh.w, ol.w);
        ((ushort4*)Dh)[(size_t)wid * F4 + f] = oh;
        ((ushort4*)Dl)[(size_t)wid * F4 + f] = ol;
    }
}

// ---------------- dual-source split-bf16 MFMA GEMM (m97 structure) ----------------
// C[i][j] = sum_k A[i][k]*B[j][k] + bias[j], A = [A1|A2] (M x 2K), B = [B1|B2] (N x 2K)
// A,B stored as bf16 hi/lo pairs; C = Ah*Bh + Ah*Bl + Al*Bh (~fp24).
// 128x128 tile, BK=32 k-positions, 256 thr = 4 waves, each wave 64x64.
// LDS staged via global_load_lds(16B); XOR swizzle chunk^=(row>>1)&3 applied on the
// GLOBAL source (linear LDS dest) and on ds_read => conflict-free-ish (2-way).
#define GBM 128
#define GBN 128
#define GBK 32

__global__ __launch_bounds__(256) void gemm_hl(
    const u16* __restrict__ A1h, const u16* __restrict__ A1l,
    const u16* __restrict__ A2h, const u16* __restrict__ A2l,
    const u16* __restrict__ B1h, const u16* __restrict__ B1l,
    const u16* __restrict__ B2h, const u16* __restrict__ B2l,
    const float* __restrict__ bias,
    float* __restrict__ Cf, u16* __restrict__ Ch, u16* __restrict__ Cl,
    int M, int K, int ldc, int doRelu)
{
    __shared__ u16 lds[16384];          // 32 KB total
    u16* sAh = lds;                     // 128 x 32
    u16* sAl = lds + 4096;
    u16* sBh = lds + 8192;
    u16* sBl = lds + 12288;

    const int tid = threadIdx.x;
    const int w = tid >> 6, l = tid & 63;
    const int wm = w >> 1, wn = w & 1;
    const int lane15 = l & 15, slot = l >> 4;
    const int row0 = blockIdx.x * GBM;
    const int col0 = blockIdx.y * GBN;

    // wave w stages one array: 0->Ah 1->Al 2->Bh 3->Bl
    const bool isA = (w < 2);
    const u16* s1 = isA ? ((w == 0) ? A1h : A1l) : ((w == 2) ? B1h : B1l);
    const u16* s2 = isA ? ((w == 0) ? A2h : A2l) : ((w == 2) ? B2h : B2l);
    u16* sbase = lds + (w << 12);
    const int lr = l >> 2;   // row within 16-row group
    const int lc = l & 3;    // 16B chunk

    f32x4 acc[4][4] = {};

    for (int kk0 = 0; kk0 < 2 * K; kk0 += GBK) {
        __syncthreads();  // prior compute done before LDS overwrite
#pragma unroll
        for (int i = 0; i < 8; ++i) {
            int r  = i * 16 + lr;                 // tile row 0..127
            int cp = lc ^ ((r >> 1) & 3);         // pre-swizzled source chunk
            int k  = kk0 + cp * 8;
            int g  = isA ? min(row0 + r, M - 1) : (col0 + r);
            const u16* src = (k < K) ? s1 : s2;
            int kk = (k < K) ? k : (k - K);
            gload_lds16(src + (size_t)g * K + kk, sbase + i * 512);
        }
        __syncthreads();  // compiler drains vmcnt before barrier

        short8v ah[4], al[4];
#pragma unroll
        for (int bi = 0; bi < 4; ++bi) {
            int r = wm * 64 + bi * 16 + lane15;
            int j = slot ^ ((r >> 1) & 3);
            ah[bi] = *(const short8v*)&sAh[r * 32 + j * 8];
            al[bi] = *(const short8v*)&sAl[r * 32 + j * 8];
        }
#pragma unroll
        for (int bj = 0; bj < 4; ++bj) {
            int c = wn * 64 + bj * 16 + lane15;
            int j = slot ^ ((c >> 1) & 3);
            short8v bh = *(const short8v*)&sBh[c * 32 + j * 8];
            short8v bl = *(const short8v*)&sBl[c * 32 + j * 8];
#pragma unroll
            for (int bi = 0; bi < 4; ++bi) {
                acc[bi][bj] = __builtin_amdgcn_mfma_f32_16x16x32_bf16(ah[bi], bh, acc[bi][bj], 0, 0, 0);
                acc[bi][bj] = __builtin_amdgcn_mfma_f32_16x16x32_bf16(ah[bi], bl, acc[bi][bj], 0, 0, 0);
                acc[bi][bj] = __builtin_amdgcn_mfma_f32_16x16x32_bf16(al[bi], bh, acc[bi][bj], 0, 0, 0);
            }
        }
    }

    // epilogue: C/D layout col=lane&15, row=(lane>>4)*4+q (verified round 2)
#pragma unroll
    for (int bj = 0; bj < 4; ++bj) {
        int cc = col0 + wn * 64 + bj * 16 + lane15;
        float bv = bias[cc];
#pragma unroll
        for (int bi = 0; bi < 4; ++bi) {
            int rbase = row0 + wm * 64 + bi * 16 + slot * 4;
#pragma unroll
            for (int q = 0; q < 4; ++q) {
                int rr = rbase + q;
                if (rr < M) {
                    float o = acc[bi][bj][q] + bv;
                    if (doRelu) o = fmaxf(o, 0.f);
                    if (Cf) {
                        Cf[(size_t)rr * ldc + cc] = o;
                    } else {
                        u16 h = bf16rn(o);
                        Ch[(size_t)rr * ldc + cc] = h;
                        Cl[(size_t)rr * ldc + cc] = bf16rn(o - bf16tof(h));
                    }
                }
            }
        }
    }
}

// ---------------- GraphNorm (F = 256) on hi/lo storage ----------------
__global__ __launch_bounds__(256) void colstats_hl(const u16* __restrict__ Hh,
                                                   const u16* __restrict__ Hl,
                                                   float* __restrict__ sums,
                                                   float* __restrict__ sqs, int N) {
    int f = threadIdx.x;
    float s = 0.f, q = 0.f;
    for (int i = blockIdx.x; i < N; i += gridDim.x) {
        float v = bf16tof(Hh[(size_t)i * 256 + f]) + bf16tof(Hl[(size_t)i * 256 + f]);
        s += v;
        q = fmaf(v, v, q);
    }
    atomicAdd(&sums[f], s);
    atomicAdd(&sqs[f], q);
}

__global__ void norm_prep(const float* __restrict__ sums, const float* __restrict__ sqs,
                          const float* __restrict__ gw, const float* __restrict__ gb,
                          const float* __restrict__ gms, float* __restrict__ scaleF,
                          float* __restrict__ shiftF, float invN) {
    int f = threadIdx.x;  // 256 threads
    float mu  = sums[f] * invN;
    float ex2 = sqs[f] * invN;
    float a   = gms[f] * mu;
    float var = ex2 - 2.f * a * mu + a * a;
    float inv = rsqrtf(var + 1e-5f);
    float sc  = gw[f] * inv;
    scaleF[f] = sc;
    shiftF[f] = gb[f] - a * sc;
}

__global__ __launch_bounds__(256) void norm_apply_hl(
    ushort4* __restrict__ Hh, ushort4* __restrict__ Hl,
    const float4* __restrict__ scaleF, const float4* __restrict__ shiftF, int n4) {
    int i = blockIdx.x * 256 + threadIdx.x;
    if (i >= n4) return;
    int f4 = i & 63;  // 256 feats = 64 ushort4 per row
    ushort4 h = Hh[i], lo = Hl[i];
    float4 sc = scaleF[f4], sh = shiftF[f4];
    float vx = fmaxf(fmaf(bf16tof(h.x) + bf16tof(lo.x), sc.x, sh.x), 0.f);
    float vy = fmaxf(fmaf(bf16tof(h.y) + bf16tof(lo.y), sc.y, sh.y), 0.f);
    float vz = fmaxf(fmaf(bf16tof(h.z) + bf16tof(lo.z), sc.z, sh.z), 0.f);
    float vw = fmaxf(fmaf(bf16tof(h.w) + bf16tof(lo.w), sc.w, sh.w), 0.f);
    ushort4 oh, ol;
    packhl(vx, oh.x, ol.x); packhl(vy, oh.y, ol.y);
    packhl(vz, oh.z, ol.z); packhl(vw, oh.w, ol.w);
    Hh[i] = oh;
    Hl[i] = ol;
}

// ---------------- launch ----------------
extern "C" void kernel_launch(void* const* d_in, const int* in_sizes, int n_in,
                              void* d_out, int out_size, void* d_ws, size_t ws_size,
                              hipStream_t stream) {
    const float* x   = (const float*)d_in[0];
    const int*   ei  = (const int*)d_in[1];
    const float* ea  = (const float*)d_in[2];
    const float* Wr1 = (const float*)d_in[3];
    const float* b1  = (const float*)d_in[4];
    const float* Wo1 = (const float*)d_in[5];
    const float* Wr2 = (const float*)d_in[6];
    const float* b2  = (const float*)d_in[7];
    const float* Wo2 = (const float*)d_in[8];
    const float* Wr3 = (const float*)d_in[9];
    const float* b3  = (const float*)d_in[10];
    const float* Wo3 = (const float*)d_in[11];
    const float* Wr4 = (const float*)d_in[12];
    const float* b4  = (const float*)d_in[13];
    const float* Wo4 = (const float*)d_in[14];
    const float* gw  = (const float*)d_in[15];
    const float* gb  = (const float*)d_in[16];
    const float* gms = (const float*)d_in[17];

    const int Nn = in_sizes[0] / F_IN;   // 50000
    const int E  = in_sizes[1] / 2;      // 400000
    const int* src = ei;
    const int* dst = ei + E;

    char* wp = (char*)d_ws;
    auto alloc = [&](size_t bytes) -> void* {
        void* p = (void*)wp;
        wp += (bytes + 255) & ~(size_t)255;
        return p;
    };
    int*   counts   = (int*)alloc((size_t)Nn * 4);
    int*   rowptr   = (int*)alloc((size_t)(Nn + 1) * 4);
    int*   fillhead = (int*)alloc((size_t)Nn * 4);
    int*   col      = (int*)alloc((size_t)E * 4);
    float* wv       = (float*)alloc((size_t)E * 4);
    float* stats    = (float*)alloc(1024 * 4);
    float* sums = stats, *sqs = stats + 256, *scaleF = stats + 512, *shiftF = stats + 768;
    // weights hi/lo
    u16* wr1h = (u16*)alloc(2u * 256 * 144); u16* wr1l = (u16*)alloc(2u * 256 * 144);
    u16* wo1h = (u16*)alloc(2u * 256 * 144); u16* wo1l = (u16*)alloc(2u * 256 * 144);
    u16* wr2h = (u16*)alloc(2u * 512 * 256); u16* wr2l = (u16*)alloc(2u * 512 * 256);
    u16* wo2h = (u16*)alloc(2u * 512 * 256); u16* wo2l = (u16*)alloc(2u * 512 * 256);
    u16* wr3h = (u16*)alloc(2u * 256 * 512); u16* wr3l = (u16*)alloc(2u * 256 * 512);
    u16* wo3h = (u16*)alloc(2u * 256 * 512); u16* wo3l = (u16*)alloc(2u * 256 * 512);
    u16* wr4h = (u16*)alloc(2u * 128 * 256); u16* wr4l = (u16*)alloc(2u * 128 * 256);
    u16* wo4h = (u16*)alloc(2u * 128 * 256); u16* wo4l = (u16*)alloc(2u * 128 * 256);
    // big regions with lifetime-based aliasing
    u16* regA = (u16*)alloc((size_t)Nn * 512 * 2 * 2);  // agg hi/lo (all layers)
    u16* regB = (u16*)alloc((size_t)Nn * 512 * 2 * 2);  // x hi/lo, then h2 hi/lo
    u16* regC = (u16*)alloc((size_t)Nn * 256 * 2 * 2);  // h1 hi/lo, then h3 hi/lo
    u16* aggH = regA,  *aggL = regA + (size_t)Nn * 512;
    u16* xh   = regB,  *xl   = regB + (size_t)Nn * 144;
    u16* h2h  = regB,  *h2l  = regB + (size_t)Nn * 512;
    u16* h1h  = regC,  *h1l  = regC + (size_t)Nn * 256;
    u16* h3h  = regC,  *h3l  = regC + (size_t)Nn * 256;

    const int TB = 256;
    // CSR build
    zero_i32<<<(Nn + TB - 1) / TB, TB, 0, stream>>>(counts, Nn);
    count_edges<<<(E + TB - 1) / TB, TB, 0, stream>>>(dst, counts, E);
    scan_counts<<<1, 1024, 0, stream>>>(counts, rowptr, Nn);
    copy_i32<<<(Nn + TB - 1) / TB, TB, 0, stream>>>(rowptr, fillhead, Nn);
    fill_edges<<<(E + TB - 1) / TB, TB, 0, stream>>>(src, dst, ea, fillhead, col, wv, E);

    // conversions
    int nx = Nn * F_IN;
    conv_hl<<<(nx + 255) / 256, 256, 0, stream>>>(x, xh, xl, nx);
    struct WC { const float* s; u16* h; u16* l; int n; } wc[8] = {
        {Wr1, wr1h, wr1l, 256 * 144}, {Wo1, wo1h, wo1l, 256 * 144},
        {Wr2, wr2h, wr2l, 512 * 256}, {Wo2, wo2h, wo2l, 512 * 256},
        {Wr3, wr3h, wr3l, 256 * 512}, {Wo3, wo3h, wo3l, 256 * 512},
        {Wr4, wr4h, wr4l, 128 * 256}, {Wo4, wo4h, wo4l, 128 * 256}};
    for (int i = 0; i < 8; ++i)
        conv_hl<<<(wc[i].n + 255) / 256, 256, 0, stream>>>(wc[i].s, wc[i].h, wc[i].l, wc[i].n);

    int aggGrid = (Nn + 3) / 4;
    int mB = (Nn + GBM - 1) / GBM;  // 391

    // Layer 1: 144 -> 256, relu
    aggregate_hl<<<aggGrid, TB, 0, stream>>>(xh, xl, rowptr, col, wv, aggH, aggL, Nn, 36);
    gemm_hl<<<dim3(mB, 2), 256, 0, stream>>>(aggH, aggL, xh, xl, wr1h, wr1l, wo1h, wo1l,
                                             b1, nullptr, h1h, h1l, Nn, 144, 256, 1);
    // Layer 2: 256 -> 512, relu   (h2 overwrites x region; x dead)
    aggregate_hl<<<aggGrid, TB, 0, stream>>>(h1h, h1l, rowptr, col, wv, aggH, aggL, Nn, 64);
    gemm_hl<<<dim3(mB, 4), 256, 0, stream>>>(aggH, aggL, h1h, h1l, wr2h, wr2l, wo2h, wo2l,
                                             b2, nullptr, h2h, h2l, Nn, 256, 512, 1);
    // Layer 3: 512 -> 256, no relu   (h3 overwrites h1; h1 dead)
    aggregate_hl<<<aggGrid, TB, 0, stream>>>(h2h, h2l, rowptr, col, wv, aggH, aggL, Nn, 128);
    gemm_hl<<<dim3(mB, 2), 256, 0, stream>>>(aggH, aggL, h2h, h2l, wr3h, wr3l, wo3h, wo3l,
                                             b3, nullptr, h3h, h3l, Nn, 512, 256, 0);
    // GraphNorm + relu in place on h3
    zero_f32<<<2, TB, 0, stream>>>(stats, 512);
    colstats_hl<<<256, TB, 0, stream>>>(h3h, h3l, sums, sqs, Nn);
    norm_prep<<<1, 256, 0, stream>>>(sums, sqs, gw, gb, gms, scaleF, shiftF, 1.0f / Nn);
    norm_apply_hl<<<(Nn * 64 + TB - 1) / TB, TB, 0, stream>>>(
        (ushort4*)h3h, (ushort4*)h3l, (const float4*)scaleF, (const float4*)shiftF, Nn * 64);
    // Layer 4: 256 -> 128, no relu, f32 out
    aggregate_hl<<<aggGrid, TB, 0, stream>>>(h3h, h3l, rowptr, col, wv, aggH, aggL, Nn, 64);
    gemm_hl<<<dim3(mB, 1), 256, 0, stream>>>(aggH, aggL, h3h, h3l, wr4h, wr4l, wo4h, wo4l,
                                             b4, (float*)d_out, nullptr, nullptr, Nn, 256, 128, 0);
}